// Round 5
// baseline (312.457 us; speedup 1.0000x reference)
//
#include <hip/hip_runtime.h>
#include <hip/hip_fp16.h>

// GCNWithJK on MI355X.
// Layers collapse to one GEMM each: W_eff = 0.95*W + 0.05*Wr (linearity of Agg).
// All activations fp16; GEMMs use v_mfma_f32_16x16x32_f16 (fp32 accum).
// CSR build: count -> scan -> XCD-partitioned fill (8 row-groups via blockIdx%8)
// writing packed {col,w} 8B records (kills the 13x scatter writeback amplification).

#define FEAT 128

typedef _Float16 half8 __attribute__((ext_vector_type(8)));
typedef _Float16 half4 __attribute__((ext_vector_type(4)));
typedef float f32x4 __attribute__((ext_vector_type(4)));

__device__ __forceinline__ int lower_bound_i(const int* a, int n, int key) {
  int lo = 0, hi = n;
  while (lo < hi) { int mid = (lo + hi) >> 1; if (a[mid] < key) lo = mid + 1; else hi = mid; }
  return lo;
}

// ---- x fp32 -> fp16 ----
__global__ void f2h(const float* __restrict__ in, __half* __restrict__ out, int n4) {
  int i = blockIdx.x * blockDim.x + threadIdx.x;
  if (i < n4) {
    float4 v = *((const float4*)in + i);
    half4 h = { (_Float16)v.x, (_Float16)v.y, (_Float16)v.z, (_Float16)v.w };
    *((half4*)out + i) = h;
  }
}

// ---- weight prep: blend + transpose -> fp16 (Wt[c][k] = 0.95*W[k][c]+0.05*Wr[k][c]) ----
__global__ void prep_weights(const float* __restrict__ w1, const float* __restrict__ wr1,
                             const float* __restrict__ b1, const float* __restrict__ br1,
                             const float* __restrict__ w2, const float* __restrict__ b2,
                             const float* __restrict__ w3, const float* __restrict__ b3,
                             const float* __restrict__ wr, const float* __restrict__ br,
                             __half* __restrict__ Wt, float* __restrict__ beff) {
  __shared__ float tile[128][129];
  int l = blockIdx.x;
  const float* W  = (l == 0) ? w1 : ((l == 1) ? w2 : w3);
  const float* Wr = (l == 0) ? wr1 : wr;
  const float* B  = (l == 0) ? b1 : ((l == 1) ? b2 : b3);
  const float* Br = (l == 0) ? br1 : br;
  int t = threadIdx.x;
  for (int idx = t; idx < 128 * 128; idx += 256) {
    int k = idx >> 7, c = idx & 127;
    tile[k][c] = 0.95f * W[idx] + 0.05f * Wr[idx];
  }
  __syncthreads();
  __half* out = Wt + l * 128 * 128;
  for (int idx = t; idx < 128 * 128; idx += 256) {
    int c = idx >> 7, k = idx & 127;
    out[idx] = __float2half(tile[k][c]);
  }
  if (t < 128) beff[l * 128 + t] = 0.95f * B[t] + 0.05f * Br[t];
}

// ---- CSR build ----
__global__ void count_edges(const int* __restrict__ row, int E, int* __restrict__ cnt) {
  int e = blockIdx.x * blockDim.x + threadIdx.x;
  if (e < E) atomicAdd(&cnt[row[e]], 1);
}

__global__ void compute_dinv(const int* __restrict__ cnt, int n, float* __restrict__ dinv) {
  int i = blockIdx.x * blockDim.x + threadIdx.x;
  if (i < n) dinv[i] = rsqrtf((float)cnt[i] + 1.0f);  // +1 self-loop
}

__global__ void scan1(const int* __restrict__ cnt, int n, int* __restrict__ bsum) {
  __shared__ int sdata[1024];
  int i = blockIdx.x * 1024 + threadIdx.x;
  sdata[threadIdx.x] = (i < n) ? cnt[i] : 0;
  __syncthreads();
  for (int s = 512; s > 0; s >>= 1) {
    if (threadIdx.x < s) sdata[threadIdx.x] += sdata[threadIdx.x + s];
    __syncthreads();
  }
  if (threadIdx.x == 0) bsum[blockIdx.x] = sdata[0];
}

__global__ void scan2(int* __restrict__ bsum, int nb, int* __restrict__ start, int n) {
  if (threadIdx.x == 0 && blockIdx.x == 0) {
    int acc = 0;
    for (int b = 0; b < nb; b++) { int v = bsum[b]; bsum[b] = acc; acc += v; }
    start[n] = acc;
  }
}

__global__ void scan3(const int* __restrict__ cnt, int n, const int* __restrict__ bsum,
                      int* __restrict__ start, int* __restrict__ cursor) {
  __shared__ int sdata[1024];
  int tid = threadIdx.x;
  int i = blockIdx.x * 1024 + tid;
  int v = (i < n) ? cnt[i] : 0;
  sdata[tid] = v;
  __syncthreads();
  for (int off = 1; off < 1024; off <<= 1) {
    int add = (tid >= off) ? sdata[tid - off] : 0;
    __syncthreads();
    sdata[tid] += add;
    __syncthreads();
  }
  if (i < n) {
    int sv = bsum[blockIdx.x] + sdata[tid] - v;  // exclusive
    start[i] = sv;
    cursor[i] = sv;
  }
}

// ---- XCD-partitioned fill: block b -> group g=b&7 (row range), slice s=b>>3 ----
// All writes to a CSR region come from one XCD -> each 64B line written back once.
__global__ __launch_bounds__(256) void fill_part(const int* __restrict__ edge, int E,
                                                 const float* __restrict__ dinv,
                                                 int* __restrict__ cursor,
                                                 int2* __restrict__ recs,
                                                 int n, int nslice) {
  int b = blockIdx.x;
  int g = b & 7;
  int s = b >> 3;
  int rpg = n >> 3;                      // 6250
  int rlo = g * rpg;
  int rhi = (g == 7) ? n : rlo + rpg;
  long long e0 = (long long)E * s / nslice;
  long long e1 = (long long)E * (s + 1) / nslice;
  for (int e = (int)e0 + threadIdx.x; e < (int)e1; e += 256) {
    int r = edge[e];
    if (r >= rlo && r < rhi) {
      int c = edge[E + e];
      int pos = atomicAdd(&cursor[r], 1);
      recs[pos] = make_int2(c, __float_as_int(dinv[r] * dinv[c]));
    }
  }
}

// ---- MFMA GEMM: xwh[r][c] = fp16( sum_k Xh[r][k] * Wt[c][k] ) ----
// 4 waves/block, 16-row strip per wave; Wt fp16 (32KB) staged in XOR-swizzled LDS.
__global__ __launch_bounds__(256) void gemm_mfma(const __half* __restrict__ Xh,
                                                 const __half* __restrict__ Wt,
                                                 __half* __restrict__ xwh, int ntile) {
  __shared__ __half Wlds[128 * 128];
  int t = threadIdx.x;
  #pragma unroll
  for (int it = 0; it < 8; it++) {
    int idx = t + it * 256;          // 2048 chunks of 16B
    int c = idx >> 4, ch = idx & 15;
    float4 v = *((const float4*)Wt + idx);
    int byte = ((c << 8) + (ch << 4)) ^ ((c & 7) << 4);
    *(float4*)((char*)Wlds + byte) = v;
  }
  __syncthreads();

  int wid = t >> 6, lane = t & 63;
  int tile = blockIdx.x * 4 + wid;
  if (tile >= ntile) return;
  int r = lane & 15, kg = lane >> 4;
  size_t rowbase = (size_t)tile * 16;

  const half8* aptr = (const half8*)(Xh + (rowbase + r) * FEAT + kg * 8);
  half8 a[4];
  #pragma unroll
  for (int ks = 0; ks < 4; ks++) a[ks] = aptr[ks * 4];   // k0 = ks*32 + kg*8

  f32x4 acc[8];
  #pragma unroll
  for (int nt = 0; nt < 8; nt++) acc[nt] = (f32x4){0.f, 0.f, 0.f, 0.f};

  #pragma unroll
  for (int nt = 0; nt < 8; nt++) {
    #pragma unroll
    for (int ks = 0; ks < 4; ks++) {
      int byte = ((((nt << 4) + r) << 8) + (ks << 6) + (kg << 4)) ^ ((r & 7) << 4);
      half8 b = *(const half8*)((const char*)Wlds + byte);
      acc[nt] = __builtin_amdgcn_mfma_f32_16x16x32_f16(a[ks], b, acc[nt], 0, 0, 0);
    }
  }

  int orow = kg * 4;
  #pragma unroll
  for (int nt = 0; nt < 8; nt++)
    #pragma unroll
    for (int j = 0; j < 4; j++)
      xwh[(rowbase + orow + j) * FEAT + (nt << 4) + r] = __float2half(acc[nt][j]);
}

// ---- pull aggregation: one wave/node, fp16 gather, packed {c,w} recs, unroll-8 ----
__global__ __launch_bounds__(256) void aggregate(
    const __half* __restrict__ xwh, const int2* __restrict__ recs,
    const int* __restrict__ start, const float* __restrict__ dinv,
    const float* __restrict__ beff, __half* __restrict__ h, int n) {
  int wave = (blockIdx.x * blockDim.x + threadIdx.x) >> 6;
  int lane = threadIdx.x & 63;
  if (wave >= n) return;
  float di = dinv[wave];
  float2 sv = __half22float2(*(const __half2*)(xwh + (size_t)wave * FEAT + lane * 2));
  float wii = di * di;
  float a0 = sv.x * wii;
  float a1 = sv.y * wii;
  int s = start[wave], e = start[wave + 1];
  int idx = s;
  for (; idx + 8 <= e; idx += 8) {
    int2 rc[8]; float2 u[8];
    #pragma unroll
    for (int q = 0; q < 8; q++) rc[q] = recs[idx + q];
    #pragma unroll
    for (int q = 0; q < 8; q++)
      u[q] = __half22float2(*(const __half2*)(xwh + (size_t)rc[q].x * FEAT + lane * 2));
    #pragma unroll
    for (int q = 0; q < 8; q++) {
      float w = __int_as_float(rc[q].y);
      a0 += u[q].x * w; a1 += u[q].y * w;
    }
  }
  for (; idx + 4 <= e; idx += 4) {
    int2 rc[4]; float2 u[4];
    #pragma unroll
    for (int q = 0; q < 4; q++) rc[q] = recs[idx + q];
    #pragma unroll
    for (int q = 0; q < 4; q++)
      u[q] = __half22float2(*(const __half2*)(xwh + (size_t)rc[q].x * FEAT + lane * 2));
    #pragma unroll
    for (int q = 0; q < 4; q++) {
      float w = __int_as_float(rc[q].y);
      a0 += u[q].x * w; a1 += u[q].y * w;
    }
  }
  for (; idx < e; idx++) {
    int2 rc = recs[idx];
    float w = __int_as_float(rc.y);
    float2 u = __half22float2(*(const __half2*)(xwh + (size_t)rc.x * FEAT + lane * 2));
    a0 += u.x * w;
    a1 += u.y * w;
  }
  float2 b = *(const float2*)(beff + lane * 2);
  a0 = fmaxf(a0 + b.x, 0.f);
  a1 = fmaxf(a1 + b.y, 0.f);
  *(__half2*)(h + (size_t)wave * FEAT + lane * 2) = __float22half2_rn(make_float2(a0, a1));
}

// ---- fused mean-pool + lin1 + relu + lin2 + log_softmax (256 threads) ----
__global__ __launch_bounds__(256) void pool_mlp(
    const __half* __restrict__ h1, const __half* __restrict__ h2,
    const __half* __restrict__ h3, const int* __restrict__ batch, int n,
    const float* __restrict__ lin1w, const float* __restrict__ lin1b,
    const float* __restrict__ lin2w, const float* __restrict__ lin2b,
    float* __restrict__ out) {
  __shared__ float part[8][384];
  __shared__ float mean[384];
  __shared__ float tvec[128];
  __shared__ float logits[10];
  __shared__ float red[2];
  int g = blockIdx.x;
  int t = threadIdx.x;   // 256 threads
  int lo = lower_bound_i(batch, n, g);
  int hi = lower_bound_i(batch, n, g + 1);
  int rg = t >> 5, f4 = t & 31;
  float s1[4] = {0,0,0,0}, s2[4] = {0,0,0,0}, s3[4] = {0,0,0,0};
  for (int i = lo + rg; i < hi; i += 8) {
    half4 v1 = *((const half4*)(h1 + (size_t)i * FEAT) + f4);
    half4 v2 = *((const half4*)(h2 + (size_t)i * FEAT) + f4);
    half4 v3 = *((const half4*)(h3 + (size_t)i * FEAT) + f4);
    #pragma unroll
    for (int q = 0; q < 4; q++) {
      s1[q] += (float)v1[q]; s2[q] += (float)v2[q]; s3[q] += (float)v3[q];
    }
  }
  #pragma unroll
  for (int q = 0; q < 4; q++) {
    part[rg][f4 * 4 + q]       = s1[q];
    part[rg][128 + f4 * 4 + q] = s2[q];
    part[rg][256 + f4 * 4 + q] = s3[q];
  }
  __syncthreads();
  float invc = 1.0f / fmaxf((float)(hi - lo), 1.0f);
  for (int j = t; j < 384; j += 256) {
    float acc = 0.f;
    #pragma unroll
    for (int r = 0; r < 8; r++) acc += part[r][j];
    mean[j] = acc * invc;
  }
  __syncthreads();
  if (t < 128) {
    float acc = lin1b[t];
    for (int k = 0; k < 384; k++) acc += mean[k] * lin1w[k * 128 + t];
    tvec[t] = fmaxf(acc, 0.f);
  }
  __syncthreads();
  if (t < 10) {
    float a = lin2b[t];
    for (int k = 0; k < 128; k++) a += tvec[k] * lin2w[k * 10 + t];
    logits[t] = a;
  }
  __syncthreads();
  if (t == 0) {
    float m = -1e30f;
    for (int j = 0; j < 10; j++) m = fmaxf(m, logits[j]);
    float se = 0.f;
    for (int j = 0; j < 10; j++) se += expf(logits[j] - m);
    red[0] = m; red[1] = logf(se);
  }
  __syncthreads();
  if (t < 10) out[g * 10 + t] = logits[t] - red[0] - red[1];
}

extern "C" void kernel_launch(void* const* d_in, const int* in_sizes, int n_in,
                              void* d_out, int out_size, void* d_ws, size_t ws_size,
                              hipStream_t stream) {
  const float* x     = (const float*)d_in[0];
  const int*   edge  = (const int*)d_in[1];
  const int*   batch = (const int*)d_in[2];
  const float* w1    = (const float*)d_in[3];
  const float* b1    = (const float*)d_in[4];
  const float* wr1   = (const float*)d_in[5];
  const float* br1   = (const float*)d_in[6];
  const float* w2    = (const float*)d_in[7];
  const float* b2    = (const float*)d_in[8];
  const float* w3    = (const float*)d_in[9];
  const float* b3    = (const float*)d_in[10];
  const float* wr    = (const float*)d_in[11];
  const float* br    = (const float*)d_in[12];
  const float* lin1w = (const float*)d_in[13];
  const float* lin1b = (const float*)d_in[14];
  const float* lin2w = (const float*)d_in[15];
  const float* lin2b = (const float*)d_in[16];

  int n  = in_sizes[0] / FEAT;   // 50000
  int E  = in_sizes[1] / 2;      // 800000
  int ng = out_size / 10;        // 512

  char* p = (char*)d_ws;
  auto carve = [&](size_t bytes) -> void* {
    void* r = (void*)p;
    p += (bytes + 255) & ~(size_t)255;
    return r;
  };
  __half* Wt      = (__half*)carve(3 * 128 * 128 * sizeof(__half));
  float*  beff    = (float*)carve(3 * 128 * sizeof(float));
  int*    cnt     = (int*)carve((size_t)n * sizeof(int));
  int*    cursor  = (int*)carve((size_t)n * sizeof(int));
  int*    start   = (int*)carve((size_t)(n + 1) * sizeof(int));
  int*    bsum    = (int*)carve(64 * sizeof(int));
  int2*   recs    = (int2*)carve((size_t)E * sizeof(int2));
  float*  dinv    = (float*)carve((size_t)n * sizeof(float));
  __half* xh      = (__half*)carve((size_t)n * FEAT * sizeof(__half));
  __half* xwh     = (__half*)carve((size_t)n * FEAT * sizeof(__half));
  __half* h1      = (__half*)carve((size_t)n * FEAT * sizeof(__half));
  __half* h2      = (__half*)carve((size_t)n * FEAT * sizeof(__half));
  __half* h3      = (__half*)carve((size_t)n * FEAT * sizeof(__half));

  hipMemsetAsync(cnt, 0, (size_t)n * sizeof(int), stream);

  prep_weights<<<3, 256, 0, stream>>>(w1, wr1, b1, br1, w2, b2, w3, b3, wr, br, Wt, beff);

  int n4 = n * FEAT / 4;
  f2h<<<(n4 + 255) / 256, 256, 0, stream>>>(x, xh, n4);

  int eb = (E + 255) / 256;
  count_edges<<<eb, 256, 0, stream>>>(edge, E, cnt);
  compute_dinv<<<(n + 255) / 256, 256, 0, stream>>>(cnt, n, dinv);
  int nb = (n + 1023) / 1024;
  scan1<<<nb, 1024, 0, stream>>>(cnt, n, bsum);
  scan2<<<1, 64, 0, stream>>>(bsum, nb, start, n);
  scan3<<<nb, 1024, 0, stream>>>(cnt, n, bsum, start, cursor);

  int nfb = 256;                        // 8 groups x 32 slices
  fill_part<<<nfb, 256, 0, stream>>>(edge, E, dinv, cursor, recs, n, nfb / 8);

  int ntile = (n + 15) / 16;            // 3125
  int gb = (ntile + 3) / 4;             // 4 waves/block
  int ab = (n * 64 + 255) / 256;

  gemm_mfma<<<gb, 256, 0, stream>>>(xh, Wt, xwh, ntile);
  aggregate<<<ab, 256, 0, stream>>>(xwh, recs, start, dinv, beff, h1, n);

  gemm_mfma<<<gb, 256, 0, stream>>>(h1, Wt + 128 * 128, xwh, ntile);
  aggregate<<<ab, 256, 0, stream>>>(xwh, recs, start, dinv, beff + 128, h2, n);

  gemm_mfma<<<gb, 256, 0, stream>>>(h2, Wt + 2 * 128 * 128, xwh, ntile);
  aggregate<<<ab, 256, 0, stream>>>(xwh, recs, start, dinv, beff + 256, h3, n);

  pool_mlp<<<ng, 256, 0, stream>>>(h1, h2, h3, batch, n, lin1w, lin1b, lin2w, lin2b,
                                   (float*)d_out);
}

// Round 6
// 267.966 us; speedup vs baseline: 1.1660x; 1.1660x over previous
//
#include <hip/hip_runtime.h>
#include <hip/hip_fp16.h>

// GCNWithJK on MI355X.
// Layers collapse to one GEMM each: W_eff = 0.95*W + 0.05*Wr (linearity of Agg).
// All activations fp16; GEMMs use v_mfma_f32_16x16x32_f16 (fp32 accum).
// CSR build: count -> scan -> XCD-partitioned fill (8 row-groups x 128 slices,
// group = blockIdx&7 -> one XCD owns each CSR region) writing packed 4B records
// {col:u16 | w:fp16} (n<65536, w in (0,1] -> fp16 safe).

#define FEAT 128

typedef _Float16 half8 __attribute__((ext_vector_type(8)));
typedef _Float16 half4 __attribute__((ext_vector_type(4)));
typedef float f32x4 __attribute__((ext_vector_type(4)));

__device__ __forceinline__ int lower_bound_i(const int* a, int n, int key) {
  int lo = 0, hi = n;
  while (lo < hi) { int mid = (lo + hi) >> 1; if (a[mid] < key) lo = mid + 1; else hi = mid; }
  return lo;
}

__device__ __forceinline__ float rec_w(unsigned int rc) {
  return (float)__builtin_bit_cast(_Float16, (unsigned short)(rc >> 16));
}

// ---- x fp32 -> fp16 ----
__global__ void f2h(const float* __restrict__ in, __half* __restrict__ out, int n4) {
  int i = blockIdx.x * blockDim.x + threadIdx.x;
  if (i < n4) {
    float4 v = *((const float4*)in + i);
    half4 h = { (_Float16)v.x, (_Float16)v.y, (_Float16)v.z, (_Float16)v.w };
    *((half4*)out + i) = h;
  }
}

// ---- weight prep: blend + transpose -> fp16 (Wt[c][k] = 0.95*W[k][c]+0.05*Wr[k][c]) ----
__global__ void prep_weights(const float* __restrict__ w1, const float* __restrict__ wr1,
                             const float* __restrict__ b1, const float* __restrict__ br1,
                             const float* __restrict__ w2, const float* __restrict__ b2,
                             const float* __restrict__ w3, const float* __restrict__ b3,
                             const float* __restrict__ wr, const float* __restrict__ br,
                             __half* __restrict__ Wt, float* __restrict__ beff) {
  __shared__ float tile[128][129];
  int l = blockIdx.x;
  const float* W  = (l == 0) ? w1 : ((l == 1) ? w2 : w3);
  const float* Wr = (l == 0) ? wr1 : wr;
  const float* B  = (l == 0) ? b1 : ((l == 1) ? b2 : b3);
  const float* Br = (l == 0) ? br1 : br;
  int t = threadIdx.x;
  for (int idx = t; idx < 128 * 128; idx += 256) {
    int k = idx >> 7, c = idx & 127;
    tile[k][c] = 0.95f * W[idx] + 0.05f * Wr[idx];
  }
  __syncthreads();
  __half* out = Wt + l * 128 * 128;
  for (int idx = t; idx < 128 * 128; idx += 256) {
    int c = idx >> 7, k = idx & 127;
    out[idx] = __float2half(tile[k][c]);
  }
  if (t < 128) beff[l * 128 + t] = 0.95f * B[t] + 0.05f * Br[t];
}

// ---- CSR build ----
__global__ void count_edges(const int* __restrict__ row, int E, int* __restrict__ cnt) {
  int e = blockIdx.x * blockDim.x + threadIdx.x;
  if (e < E) atomicAdd(&cnt[row[e]], 1);
}

__global__ void compute_dinv(const int* __restrict__ cnt, int n, float* __restrict__ dinv) {
  int i = blockIdx.x * blockDim.x + threadIdx.x;
  if (i < n) dinv[i] = rsqrtf((float)cnt[i] + 1.0f);  // +1 self-loop
}

__global__ void scan1(const int* __restrict__ cnt, int n, int* __restrict__ bsum) {
  __shared__ int sdata[1024];
  int i = blockIdx.x * 1024 + threadIdx.x;
  sdata[threadIdx.x] = (i < n) ? cnt[i] : 0;
  __syncthreads();
  for (int s = 512; s > 0; s >>= 1) {
    if (threadIdx.x < s) sdata[threadIdx.x] += sdata[threadIdx.x + s];
    __syncthreads();
  }
  if (threadIdx.x == 0) bsum[blockIdx.x] = sdata[0];
}

__global__ void scan2(int* __restrict__ bsum, int nb, int* __restrict__ start, int n) {
  if (threadIdx.x == 0 && blockIdx.x == 0) {
    int acc = 0;
    for (int b = 0; b < nb; b++) { int v = bsum[b]; bsum[b] = acc; acc += v; }
    start[n] = acc;
  }
}

__global__ void scan3(const int* __restrict__ cnt, int n, const int* __restrict__ bsum,
                      int* __restrict__ start, int* __restrict__ cursor) {
  __shared__ int sdata[1024];
  int tid = threadIdx.x;
  int i = blockIdx.x * 1024 + tid;
  int v = (i < n) ? cnt[i] : 0;
  sdata[tid] = v;
  __syncthreads();
  for (int off = 1; off < 1024; off <<= 1) {
    int add = (tid >= off) ? sdata[tid - off] : 0;
    __syncthreads();
    sdata[tid] += add;
    __syncthreads();
  }
  if (i < n) {
    int sv = bsum[blockIdx.x] + sdata[tid] - v;  // exclusive
    start[i] = sv;
    cursor[i] = sv;
  }
}

// ---- XCD-partitioned fill: block b -> group g=b&7 (row range), slice s=b>>3 ----
// 1024 blocks (4/CU) for latency hiding; packed 4B rec = col | (fp16(w)<<16).
__global__ __launch_bounds__(256) void fill_part(const int* __restrict__ edge, int E,
                                                 const float* __restrict__ dinv,
                                                 int* __restrict__ cursor,
                                                 unsigned int* __restrict__ recs,
                                                 int n, int nslice) {
  int b = blockIdx.x;
  int g = b & 7;
  int s = b >> 3;
  int rpg = n >> 3;                      // 6250
  int rlo = g * rpg;
  int rhi = (g == 7) ? n : rlo + rpg;
  long long e0 = (long long)E * s / nslice;
  long long e1 = (long long)E * (s + 1) / nslice;
  for (int e = (int)e0 + threadIdx.x; e < (int)e1; e += 256) {
    int r = edge[e];
    if (r >= rlo && r < rhi) {
      int c = edge[E + e];
      int pos = atomicAdd(&cursor[r], 1);
      unsigned short wb = __builtin_bit_cast(unsigned short, (_Float16)(dinv[r] * dinv[c]));
      recs[pos] = (unsigned int)c | ((unsigned int)wb << 16);
    }
  }
}

// ---- MFMA GEMM: xwh[r][c] = fp16( sum_k Xh[r][k] * Wt[c][k] ) ----
// 4 waves/block, 16-row strip per wave; Wt fp16 (32KB) staged in XOR-swizzled LDS.
__global__ __launch_bounds__(256) void gemm_mfma(const __half* __restrict__ Xh,
                                                 const __half* __restrict__ Wt,
                                                 __half* __restrict__ xwh, int ntile) {
  __shared__ __half Wlds[128 * 128];
  int t = threadIdx.x;
  #pragma unroll
  for (int it = 0; it < 8; it++) {
    int idx = t + it * 256;          // 2048 chunks of 16B
    int c = idx >> 4, ch = idx & 15;
    float4 v = *((const float4*)Wt + idx);
    int byte = ((c << 8) + (ch << 4)) ^ ((c & 7) << 4);
    *(float4*)((char*)Wlds + byte) = v;
  }
  __syncthreads();

  int wid = t >> 6, lane = t & 63;
  int tile = blockIdx.x * 4 + wid;
  if (tile >= ntile) return;
  int r = lane & 15, kg = lane >> 4;
  size_t rowbase = (size_t)tile * 16;

  const half8* aptr = (const half8*)(Xh + (rowbase + r) * FEAT + kg * 8);
  half8 a[4];
  #pragma unroll
  for (int ks = 0; ks < 4; ks++) a[ks] = aptr[ks * 4];   // k0 = ks*32 + kg*8

  f32x4 acc[8];
  #pragma unroll
  for (int nt = 0; nt < 8; nt++) acc[nt] = (f32x4){0.f, 0.f, 0.f, 0.f};

  #pragma unroll
  for (int nt = 0; nt < 8; nt++) {
    #pragma unroll
    for (int ks = 0; ks < 4; ks++) {
      int byte = ((((nt << 4) + r) << 8) + (ks << 6) + (kg << 4)) ^ ((r & 7) << 4);
      half8 b = *(const half8*)((const char*)Wlds + byte);
      acc[nt] = __builtin_amdgcn_mfma_f32_16x16x32_f16(a[ks], b, acc[nt], 0, 0, 0);
    }
  }

  int orow = kg * 4;
  #pragma unroll
  for (int nt = 0; nt < 8; nt++)
    #pragma unroll
    for (int j = 0; j < 4; j++)
      xwh[(rowbase + orow + j) * FEAT + (nt << 4) + r] = __float2half(acc[nt][j]);
}

// ---- pull aggregation: one wave/node, fp16 gather, packed 4B recs, unroll-8 ----
__global__ __launch_bounds__(256) void aggregate(
    const __half* __restrict__ xwh, const unsigned int* __restrict__ recs,
    const int* __restrict__ start, const float* __restrict__ dinv,
    const float* __restrict__ beff, __half* __restrict__ h, int n) {
  int wave = (blockIdx.x * blockDim.x + threadIdx.x) >> 6;
  int lane = threadIdx.x & 63;
  if (wave >= n) return;
  float di = dinv[wave];
  float2 sv = __half22float2(*(const __half2*)(xwh + (size_t)wave * FEAT + lane * 2));
  float wii = di * di;
  float a0 = sv.x * wii;
  float a1 = sv.y * wii;
  int s = start[wave], e = start[wave + 1];
  int idx = s;
  for (; idx + 8 <= e; idx += 8) {
    unsigned int rc[8]; float2 u[8];
    #pragma unroll
    for (int q = 0; q < 8; q++) rc[q] = recs[idx + q];
    #pragma unroll
    for (int q = 0; q < 8; q++)
      u[q] = __half22float2(
          *(const __half2*)(xwh + (size_t)(rc[q] & 0xffffu) * FEAT + lane * 2));
    #pragma unroll
    for (int q = 0; q < 8; q++) {
      float w = rec_w(rc[q]);
      a0 += u[q].x * w; a1 += u[q].y * w;
    }
  }
  for (; idx + 4 <= e; idx += 4) {
    unsigned int rc[4]; float2 u[4];
    #pragma unroll
    for (int q = 0; q < 4; q++) rc[q] = recs[idx + q];
    #pragma unroll
    for (int q = 0; q < 4; q++)
      u[q] = __half22float2(
          *(const __half2*)(xwh + (size_t)(rc[q] & 0xffffu) * FEAT + lane * 2));
    #pragma unroll
    for (int q = 0; q < 4; q++) {
      float w = rec_w(rc[q]);
      a0 += u[q].x * w; a1 += u[q].y * w;
    }
  }
  for (; idx < e; idx++) {
    unsigned int rc = recs[idx];
    float w = rec_w(rc);
    float2 u = __half22float2(
        *(const __half2*)(xwh + (size_t)(rc & 0xffffu) * FEAT + lane * 2));
    a0 += u.x * w;
    a1 += u.y * w;
  }
  float2 b = *(const float2*)(beff + lane * 2);
  a0 = fmaxf(a0 + b.x, 0.f);
  a1 = fmaxf(a1 + b.y, 0.f);
  *(__half2*)(h + (size_t)wave * FEAT + lane * 2) = __float22half2_rn(make_float2(a0, a1));
}

// ---- fused mean-pool + lin1 + relu + lin2 + log_softmax (256 threads) ----
__global__ __launch_bounds__(256) void pool_mlp(
    const __half* __restrict__ h1, const __half* __restrict__ h2,
    const __half* __restrict__ h3, const int* __restrict__ batch, int n,
    const float* __restrict__ lin1w, const float* __restrict__ lin1b,
    const float* __restrict__ lin2w, const float* __restrict__ lin2b,
    float* __restrict__ out) {
  __shared__ float part[8][384];
  __shared__ float mean[384];
  __shared__ float tvec[128];
  __shared__ float logits[10];
  __shared__ float red[2];
  int g = blockIdx.x;
  int t = threadIdx.x;   // 256 threads
  int lo = lower_bound_i(batch, n, g);
  int hi = lower_bound_i(batch, n, g + 1);
  int rg = t >> 5, f4 = t & 31;
  float s1[4] = {0,0,0,0}, s2[4] = {0,0,0,0}, s3[4] = {0,0,0,0};
  for (int i = lo + rg; i < hi; i += 8) {
    half4 v1 = *((const half4*)(h1 + (size_t)i * FEAT) + f4);
    half4 v2 = *((const half4*)(h2 + (size_t)i * FEAT) + f4);
    half4 v3 = *((const half4*)(h3 + (size_t)i * FEAT) + f4);
    #pragma unroll
    for (int q = 0; q < 4; q++) {
      s1[q] += (float)v1[q]; s2[q] += (float)v2[q]; s3[q] += (float)v3[q];
    }
  }
  #pragma unroll
  for (int q = 0; q < 4; q++) {
    part[rg][f4 * 4 + q]       = s1[q];
    part[rg][128 + f4 * 4 + q] = s2[q];
    part[rg][256 + f4 * 4 + q] = s3[q];
  }
  __syncthreads();
  float invc = 1.0f / fmaxf((float)(hi - lo), 1.0f);
  for (int j = t; j < 384; j += 256) {
    float acc = 0.f;
    #pragma unroll
    for (int r = 0; r < 8; r++) acc += part[r][j];
    mean[j] = acc * invc;
  }
  __syncthreads();
  if (t < 128) {
    float acc = lin1b[t];
    for (int k = 0; k < 384; k++) acc += mean[k] * lin1w[k * 128 + t];
    tvec[t] = fmaxf(acc, 0.f);
  }
  __syncthreads();
  if (t < 10) {
    float a = lin2b[t];
    for (int k = 0; k < 128; k++) a += tvec[k] * lin2w[k * 10 + t];
    logits[t] = a;
  }
  __syncthreads();
  if (t == 0) {
    float m = -1e30f;
    for (int j = 0; j < 10; j++) m = fmaxf(m, logits[j]);
    float se = 0.f;
    for (int j = 0; j < 10; j++) se += expf(logits[j] - m);
    red[0] = m; red[1] = logf(se);
  }
  __syncthreads();
  if (t < 10) out[g * 10 + t] = logits[t] - red[0] - red[1];
}

extern "C" void kernel_launch(void* const* d_in, const int* in_sizes, int n_in,
                              void* d_out, int out_size, void* d_ws, size_t ws_size,
                              hipStream_t stream) {
  const float* x     = (const float*)d_in[0];
  const int*   edge  = (const int*)d_in[1];
  const int*   batch = (const int*)d_in[2];
  const float* w1    = (const float*)d_in[3];
  const float* b1    = (const float*)d_in[4];
  const float* wr1   = (const float*)d_in[5];
  const float* br1   = (const float*)d_in[6];
  const float* w2    = (const float*)d_in[7];
  const float* b2    = (const float*)d_in[8];
  const float* w3    = (const float*)d_in[9];
  const float* b3    = (const float*)d_in[10];
  const float* wr    = (const float*)d_in[11];
  const float* br    = (const float*)d_in[12];
  const float* lin1w = (const float*)d_in[13];
  const float* lin1b = (const float*)d_in[14];
  const float* lin2w = (const float*)d_in[15];
  const float* lin2b = (const float*)d_in[16];

  int n  = in_sizes[0] / FEAT;   // 50000
  int E  = in_sizes[1] / 2;      // 800000
  int ng = out_size / 10;        // 512

  char* p = (char*)d_ws;
  auto carve = [&](size_t bytes) -> void* {
    void* r = (void*)p;
    p += (bytes + 255) & ~(size_t)255;
    return r;
  };
  __half*       Wt     = (__half*)carve(3 * 128 * 128 * sizeof(__half));
  float*        beff   = (float*)carve(3 * 128 * sizeof(float));
  int*          cnt    = (int*)carve((size_t)n * sizeof(int));
  int*          cursor = (int*)carve((size_t)n * sizeof(int));
  int*          start  = (int*)carve((size_t)(n + 1) * sizeof(int));
  int*          bsum   = (int*)carve(64 * sizeof(int));
  unsigned int* recs   = (unsigned int*)carve((size_t)E * sizeof(unsigned int));
  float*        dinv   = (float*)carve((size_t)n * sizeof(float));
  __half*       xh     = (__half*)carve((size_t)n * FEAT * sizeof(__half));
  __half*       xwh    = (__half*)carve((size_t)n * FEAT * sizeof(__half));
  __half*       h1     = (__half*)carve((size_t)n * FEAT * sizeof(__half));
  __half*       h2     = (__half*)carve((size_t)n * FEAT * sizeof(__half));
  __half*       h3     = (__half*)carve((size_t)n * FEAT * sizeof(__half));

  hipMemsetAsync(cnt, 0, (size_t)n * sizeof(int), stream);

  prep_weights<<<3, 256, 0, stream>>>(w1, wr1, b1, br1, w2, b2, w3, b3, wr, br, Wt, beff);

  int n4 = n * FEAT / 4;
  f2h<<<(n4 + 255) / 256, 256, 0, stream>>>(x, xh, n4);

  int eb = (E + 255) / 256;
  count_edges<<<eb, 256, 0, stream>>>(edge, E, cnt);
  compute_dinv<<<(n + 255) / 256, 256, 0, stream>>>(cnt, n, dinv);
  int nb = (n + 1023) / 1024;
  scan1<<<nb, 1024, 0, stream>>>(cnt, n, bsum);
  scan2<<<1, 64, 0, stream>>>(bsum, nb, start, n);
  scan3<<<nb, 1024, 0, stream>>>(cnt, n, bsum, start, cursor);

  int nslice = 128;                     // 8 groups x 128 slices = 1024 blocks (4/CU)
  fill_part<<<8 * nslice, 256, 0, stream>>>(edge, E, dinv, cursor, recs, n, nslice);

  int ntile = (n + 15) / 16;            // 3125
  int gb = (ntile + 3) / 4;             // 4 waves/block
  int ab = (n * 64 + 255) / 256;

  gemm_mfma<<<gb, 256, 0, stream>>>(xh, Wt, xwh, ntile);
  aggregate<<<ab, 256, 0, stream>>>(xwh, recs, start, dinv, beff, h1, n);

  gemm_mfma<<<gb, 256, 0, stream>>>(h1, Wt + 128 * 128, xwh, ntile);
  aggregate<<<ab, 256, 0, stream>>>(xwh, recs, start, dinv, beff + 128, h2, n);

  gemm_mfma<<<gb, 256, 0, stream>>>(h2, Wt + 2 * 128 * 128, xwh, ntile);
  aggregate<<<ab, 256, 0, stream>>>(xwh, recs, start, dinv, beff + 256, h3, n);

  pool_mlp<<<ng, 256, 0, stream>>>(h1, h2, h3, batch, n, lin1w, lin1b, lin2w, lin2b,
                                   (float*)d_out);
}

// Round 7
// 265.947 us; speedup vs baseline: 1.1749x; 1.0076x over previous
//
#include <hip/hip_runtime.h>
#include <hip/hip_fp16.h>

// GCNWithJK on MI355X.
// Layers collapse to one GEMM each: W_eff = 0.95*W + 0.05*Wr (linearity of Agg).
// All activations fp16; GEMMs use v_mfma_f32_16x16x32_f16 (fp32 accum).
// CSR build: count -> padded scan (rows padded to x16 with zero-recs) ->
// XCD-partitioned fill (group=blockIdx&7 pins each CSR region to one XCD; edge
// streams use non-temporal loads so dirty recs lines survive in L2).
// Aggregate: one wave/node, always 16 gathers in flight (no serial tail).

#define FEAT 128

typedef _Float16 half8 __attribute__((ext_vector_type(8)));
typedef _Float16 half4 __attribute__((ext_vector_type(4)));
typedef float f32x4 __attribute__((ext_vector_type(4)));

__device__ __forceinline__ int lower_bound_i(const int* a, int n, int key) {
  int lo = 0, hi = n;
  while (lo < hi) { int mid = (lo + hi) >> 1; if (a[mid] < key) lo = mid + 1; else hi = mid; }
  return lo;
}

__device__ __forceinline__ float rec_w(unsigned int rc) {
  return (float)__builtin_bit_cast(_Float16, (unsigned short)(rc >> 16));
}

// ---- x fp32 -> fp16 ----
__global__ void f2h(const float* __restrict__ in, __half* __restrict__ out, int n4) {
  int i = blockIdx.x * blockDim.x + threadIdx.x;
  if (i < n4) {
    float4 v = *((const float4*)in + i);
    half4 h = { (_Float16)v.x, (_Float16)v.y, (_Float16)v.z, (_Float16)v.w };
    *((half4*)out + i) = h;
  }
}

// ---- weight prep: blend + transpose -> fp16 (Wt[c][k] = 0.95*W[k][c]+0.05*Wr[k][c]) ----
__global__ void prep_weights(const float* __restrict__ w1, const float* __restrict__ wr1,
                             const float* __restrict__ b1, const float* __restrict__ br1,
                             const float* __restrict__ w2, const float* __restrict__ b2,
                             const float* __restrict__ w3, const float* __restrict__ b3,
                             const float* __restrict__ wr, const float* __restrict__ br,
                             __half* __restrict__ Wt, float* __restrict__ beff) {
  __shared__ float tile[128][129];
  int l = blockIdx.x;
  const float* W  = (l == 0) ? w1 : ((l == 1) ? w2 : w3);
  const float* Wr = (l == 0) ? wr1 : wr;
  const float* B  = (l == 0) ? b1 : ((l == 1) ? b2 : b3);
  const float* Br = (l == 0) ? br1 : br;
  int t = threadIdx.x;
  for (int idx = t; idx < 128 * 128; idx += 256) {
    int k = idx >> 7, c = idx & 127;
    tile[k][c] = 0.95f * W[idx] + 0.05f * Wr[idx];
  }
  __syncthreads();
  __half* out = Wt + l * 128 * 128;
  for (int idx = t; idx < 128 * 128; idx += 256) {
    int c = idx >> 7, k = idx & 127;
    out[idx] = __float2half(tile[k][c]);
  }
  if (t < 128) beff[l * 128 + t] = 0.95f * B[t] + 0.05f * Br[t];
}

// ---- CSR build ----
__global__ void count_edges(const int* __restrict__ row, int E, int* __restrict__ cnt) {
  int e = blockIdx.x * blockDim.x + threadIdx.x;
  if (e < E) atomicAdd(&cnt[__builtin_nontemporal_load(&row[e])], 1);
}

__global__ void compute_dinv(const int* __restrict__ cnt, int n, float* __restrict__ dinv) {
  int i = blockIdx.x * blockDim.x + threadIdx.x;
  if (i < n) dinv[i] = rsqrtf((float)cnt[i] + 1.0f);  // +1 self-loop
}

// padded count: round each row up to a multiple of 16 (zero-recs fill the gap)
__global__ void scan1(const int* __restrict__ cnt, int n, int* __restrict__ bsum) {
  __shared__ int sdata[1024];
  int i = blockIdx.x * 1024 + threadIdx.x;
  sdata[threadIdx.x] = (i < n) ? ((cnt[i] + 15) & ~15) : 0;
  __syncthreads();
  for (int s = 512; s > 0; s >>= 1) {
    if (threadIdx.x < s) sdata[threadIdx.x] += sdata[threadIdx.x + s];
    __syncthreads();
  }
  if (threadIdx.x == 0) bsum[blockIdx.x] = sdata[0];
}

__global__ void scan2(int* __restrict__ bsum, int nb, int* __restrict__ start, int n) {
  if (threadIdx.x == 0 && blockIdx.x == 0) {
    int acc = 0;
    for (int b = 0; b < nb; b++) { int v = bsum[b]; bsum[b] = acc; acc += v; }
    start[n] = acc;
  }
}

__global__ void scan3(const int* __restrict__ cnt, int n, const int* __restrict__ bsum,
                      int* __restrict__ start, int* __restrict__ cursor) {
  __shared__ int sdata[1024];
  int tid = threadIdx.x;
  int i = blockIdx.x * 1024 + tid;
  int v = (i < n) ? ((cnt[i] + 15) & ~15) : 0;
  sdata[tid] = v;
  __syncthreads();
  for (int off = 1; off < 1024; off <<= 1) {
    int add = (tid >= off) ? sdata[tid - off] : 0;
    __syncthreads();
    sdata[tid] += add;
    __syncthreads();
  }
  if (i < n) {
    int sv = bsum[blockIdx.x] + sdata[tid] - v;  // exclusive (padded)
    start[i] = sv;
    cursor[i] = sv;
  }
}

// ---- XCD-partitioned fill: block b -> group g=b&7 (row range), slice s=b>>3 ----
// 2048 blocks (8/CU); non-temporal edge loads keep dirty recs lines resident in L2.
__global__ __launch_bounds__(256) void fill_part(const int* __restrict__ edge, int E,
                                                 const float* __restrict__ dinv,
                                                 int* __restrict__ cursor,
                                                 unsigned int* __restrict__ recs,
                                                 int n, int nslice) {
  int b = blockIdx.x;
  int g = b & 7;
  int s = b >> 3;
  int rpg = n >> 3;                      // 6250
  int rlo = g * rpg;
  int rhi = (g == 7) ? n : rlo + rpg;
  long long e0 = (long long)E * s / nslice;
  long long e1 = (long long)E * (s + 1) / nslice;
  for (int e = (int)e0 + threadIdx.x; e < (int)e1; e += 256) {
    int r = __builtin_nontemporal_load(&edge[e]);
    if (r >= rlo && r < rhi) {
      int c = __builtin_nontemporal_load(&edge[E + e]);
      int pos = atomicAdd(&cursor[r], 1);
      unsigned short wb = __builtin_bit_cast(unsigned short, (_Float16)(dinv[r] * dinv[c]));
      recs[pos] = (unsigned int)c | ((unsigned int)wb << 16);
    }
  }
}

// ---- MFMA GEMM: xwh[r][c] = fp16( sum_k Xh[r][k] * Wt[c][k] ) ----
// 4 waves/block, 16-row strip per wave; Wt fp16 (32KB) staged in XOR-swizzled LDS.
__global__ __launch_bounds__(256) void gemm_mfma(const __half* __restrict__ Xh,
                                                 const __half* __restrict__ Wt,
                                                 __half* __restrict__ xwh, int ntile) {
  __shared__ __half Wlds[128 * 128];
  int t = threadIdx.x;
  #pragma unroll
  for (int it = 0; it < 8; it++) {
    int idx = t + it * 256;          // 2048 chunks of 16B
    int c = idx >> 4, ch = idx & 15;
    float4 v = *((const float4*)Wt + idx);
    int byte = ((c << 8) + (ch << 4)) ^ ((c & 7) << 4);
    *(float4*)((char*)Wlds + byte) = v;
  }
  __syncthreads();

  int wid = t >> 6, lane = t & 63;
  int tile = blockIdx.x * 4 + wid;
  if (tile >= ntile) return;
  int r = lane & 15, kg = lane >> 4;
  size_t rowbase = (size_t)tile * 16;

  const half8* aptr = (const half8*)(Xh + (rowbase + r) * FEAT + kg * 8);
  half8 a[4];
  #pragma unroll
  for (int ks = 0; ks < 4; ks++) a[ks] = aptr[ks * 4];   // k0 = ks*32 + kg*8

  f32x4 acc[8];
  #pragma unroll
  for (int nt = 0; nt < 8; nt++) acc[nt] = (f32x4){0.f, 0.f, 0.f, 0.f};

  #pragma unroll
  for (int nt = 0; nt < 8; nt++) {
    #pragma unroll
    for (int ks = 0; ks < 4; ks++) {
      int byte = ((((nt << 4) + r) << 8) + (ks << 6) + (kg << 4)) ^ ((r & 7) << 4);
      half8 b = *(const half8*)((const char*)Wlds + byte);
      acc[nt] = __builtin_amdgcn_mfma_f32_16x16x32_f16(a[ks], b, acc[nt], 0, 0, 0);
    }
  }

  int orow = kg * 4;
  #pragma unroll
  for (int nt = 0; nt < 8; nt++)
    #pragma unroll
    for (int j = 0; j < 4; j++)
      xwh[(rowbase + orow + j) * FEAT + (nt << 4) + r] = __float2half(acc[nt][j]);
}

// ---- pull aggregation: one wave/node; rows padded to x16 -> always 16 gathers
// in flight, zero serial tail (pad recs gather row 0 with w=0: exact no-op) ----
__global__ __launch_bounds__(256) void aggregate(
    const __half* __restrict__ xwh, const unsigned int* __restrict__ recs,
    const int* __restrict__ start, const float* __restrict__ dinv,
    const float* __restrict__ beff, __half* __restrict__ h, int n) {
  int wave = (blockIdx.x * blockDim.x + threadIdx.x) >> 6;
  int lane = threadIdx.x & 63;
  if (wave >= n) return;
  float di = dinv[wave];
  float2 sv = __half22float2(*(const __half2*)(xwh + (size_t)wave * FEAT + lane * 2));
  float wii = di * di;
  float a0 = sv.x * wii;
  float a1 = sv.y * wii;
  int s = start[wave], e = start[wave + 1];   // e - s is a multiple of 16
  for (int idx = s; idx < e; idx += 16) {
    uint4 r0 = *(const uint4*)(recs + idx);
    uint4 r1 = *(const uint4*)(recs + idx + 4);
    uint4 r2 = *(const uint4*)(recs + idx + 8);
    uint4 r3 = *(const uint4*)(recs + idx + 12);
    unsigned int rc[16] = {r0.x, r0.y, r0.z, r0.w, r1.x, r1.y, r1.z, r1.w,
                           r2.x, r2.y, r2.z, r2.w, r3.x, r3.y, r3.z, r3.w};
    float2 u[16];
    #pragma unroll
    for (int q = 0; q < 16; q++)
      u[q] = __half22float2(
          *(const __half2*)(xwh + (size_t)(rc[q] & 0xffffu) * FEAT + lane * 2));
    #pragma unroll
    for (int q = 0; q < 16; q++) {
      float w = rec_w(rc[q]);
      a0 += u[q].x * w; a1 += u[q].y * w;
    }
  }
  float2 b = *(const float2*)(beff + lane * 2);
  a0 = fmaxf(a0 + b.x, 0.f);
  a1 = fmaxf(a1 + b.y, 0.f);
  *(__half2*)(h + (size_t)wave * FEAT + lane * 2) = __float22half2_rn(make_float2(a0, a1));
}

// ---- fused mean-pool + lin1 + relu + lin2 + log_softmax (256 threads) ----
__global__ __launch_bounds__(256) void pool_mlp(
    const __half* __restrict__ h1, const __half* __restrict__ h2,
    const __half* __restrict__ h3, const int* __restrict__ batch, int n,
    const float* __restrict__ lin1w, const float* __restrict__ lin1b,
    const float* __restrict__ lin2w, const float* __restrict__ lin2b,
    float* __restrict__ out) {
  __shared__ float part[8][384];
  __shared__ float mean[384];
  __shared__ float tvec[128];
  __shared__ float logits[10];
  __shared__ float red[2];
  int g = blockIdx.x;
  int t = threadIdx.x;   // 256 threads
  int lo = lower_bound_i(batch, n, g);
  int hi = lower_bound_i(batch, n, g + 1);
  int rg = t >> 5, f4 = t & 31;
  float s1[4] = {0,0,0,0}, s2[4] = {0,0,0,0}, s3[4] = {0,0,0,0};
  for (int i = lo + rg; i < hi; i += 8) {
    half4 v1 = *((const half4*)(h1 + (size_t)i * FEAT) + f4);
    half4 v2 = *((const half4*)(h2 + (size_t)i * FEAT) + f4);
    half4 v3 = *((const half4*)(h3 + (size_t)i * FEAT) + f4);
    #pragma unroll
    for (int q = 0; q < 4; q++) {
      s1[q] += (float)v1[q]; s2[q] += (float)v2[q]; s3[q] += (float)v3[q];
    }
  }
  #pragma unroll
  for (int q = 0; q < 4; q++) {
    part[rg][f4 * 4 + q]       = s1[q];
    part[rg][128 + f4 * 4 + q] = s2[q];
    part[rg][256 + f4 * 4 + q] = s3[q];
  }
  __syncthreads();
  float invc = 1.0f / fmaxf((float)(hi - lo), 1.0f);
  for (int j = t; j < 384; j += 256) {
    float acc = 0.f;
    #pragma unroll
    for (int r = 0; r < 8; r++) acc += part[r][j];
    mean[j] = acc * invc;
  }
  __syncthreads();
  if (t < 128) {
    float acc = lin1b[t];
    for (int k = 0; k < 384; k++) acc += mean[k] * lin1w[k * 128 + t];
    tvec[t] = fmaxf(acc, 0.f);
  }
  __syncthreads();
  if (t < 10) {
    float a = lin2b[t];
    for (int k = 0; k < 128; k++) a += tvec[k] * lin2w[k * 10 + t];
    logits[t] = a;
  }
  __syncthreads();
  if (t == 0) {
    float m = -1e30f;
    for (int j = 0; j < 10; j++) m = fmaxf(m, logits[j]);
    float se = 0.f;
    for (int j = 0; j < 10; j++) se += expf(logits[j] - m);
    red[0] = m; red[1] = logf(se);
  }
  __syncthreads();
  if (t < 10) out[g * 10 + t] = logits[t] - red[0] - red[1];
}

extern "C" void kernel_launch(void* const* d_in, const int* in_sizes, int n_in,
                              void* d_out, int out_size, void* d_ws, size_t ws_size,
                              hipStream_t stream) {
  const float* x     = (const float*)d_in[0];
  const int*   edge  = (const int*)d_in[1];
  const int*   batch = (const int*)d_in[2];
  const float* w1    = (const float*)d_in[3];
  const float* b1    = (const float*)d_in[4];
  const float* wr1   = (const float*)d_in[5];
  const float* br1   = (const float*)d_in[6];
  const float* w2    = (const float*)d_in[7];
  const float* b2    = (const float*)d_in[8];
  const float* w3    = (const float*)d_in[9];
  const float* b3    = (const float*)d_in[10];
  const float* wr    = (const float*)d_in[11];
  const float* br    = (const float*)d_in[12];
  const float* lin1w = (const float*)d_in[13];
  const float* lin1b = (const float*)d_in[14];
  const float* lin2w = (const float*)d_in[15];
  const float* lin2b = (const float*)d_in[16];

  int n  = in_sizes[0] / FEAT;   // 50000
  int E  = in_sizes[1] / 2;      // 800000
  int ng = out_size / 10;        // 512

  char* p = (char*)d_ws;
  auto carve = [&](size_t bytes) -> void* {
    void* r = (void*)p;
    p += (bytes + 255) & ~(size_t)255;
    return r;
  };
  size_t recs_cap = (size_t)E + 16 * (size_t)n;   // padded upper bound
  __half*       Wt     = (__half*)carve(3 * 128 * 128 * sizeof(__half));
  float*        beff   = (float*)carve(3 * 128 * sizeof(float));
  int*          cnt    = (int*)carve((size_t)n * sizeof(int));
  int*          cursor = (int*)carve((size_t)n * sizeof(int));
  int*          start  = (int*)carve((size_t)(n + 1) * sizeof(int));
  int*          bsum   = (int*)carve(64 * sizeof(int));
  unsigned int* recs   = (unsigned int*)carve(recs_cap * sizeof(unsigned int));
  float*        dinv   = (float*)carve((size_t)n * sizeof(float));
  __half*       xh     = (__half*)carve((size_t)n * FEAT * sizeof(__half));
  __half*       xwh    = (__half*)carve((size_t)n * FEAT * sizeof(__half));
  __half*       h1     = (__half*)carve((size_t)n * FEAT * sizeof(__half));
  __half*       h2     = (__half*)carve((size_t)n * FEAT * sizeof(__half));
  __half*       h3     = (__half*)carve((size_t)n * FEAT * sizeof(__half));

  hipMemsetAsync(cnt, 0, (size_t)n * sizeof(int), stream);
  hipMemsetAsync(recs, 0, recs_cap * sizeof(unsigned int), stream);

  prep_weights<<<3, 256, 0, stream>>>(w1, wr1, b1, br1, w2, b2, w3, b3, wr, br, Wt, beff);

  int n4 = n * FEAT / 4;
  f2h<<<(n4 + 255) / 256, 256, 0, stream>>>(x, xh, n4);

  int eb = (E + 255) / 256;
  count_edges<<<eb, 256, 0, stream>>>(edge, E, cnt);
  compute_dinv<<<(n + 255) / 256, 256, 0, stream>>>(cnt, n, dinv);
  int nb = (n + 1023) / 1024;
  scan1<<<nb, 1024, 0, stream>>>(cnt, n, bsum);
  scan2<<<1, 64, 0, stream>>>(bsum, nb, start, n);
  scan3<<<nb, 1024, 0, stream>>>(cnt, n, bsum, start, cursor);

  int nslice = 256;                     // 8 groups x 256 slices = 2048 blocks (8/CU)
  fill_part<<<8 * nslice, 256, 0, stream>>>(edge, E, dinv, cursor, recs, n, nslice);

  int ntile = (n + 15) / 16;            // 3125
  int gb = (ntile + 3) / 4;             // 4 waves/block
  int ab = (n * 64 + 255) / 256;

  gemm_mfma<<<gb, 256, 0, stream>>>(xh, Wt, xwh, ntile);
  aggregate<<<ab, 256, 0, stream>>>(xwh, recs, start, dinv, beff, h1, n);

  gemm_mfma<<<gb, 256, 0, stream>>>(h1, Wt + 128 * 128, xwh, ntile);
  aggregate<<<ab, 256, 0, stream>>>(xwh, recs, start, dinv, beff + 128, h2, n);

  gemm_mfma<<<gb, 256, 0, stream>>>(h2, Wt + 2 * 128 * 128, xwh, ntile);
  aggregate<<<ab, 256, 0, stream>>>(xwh, recs, start, dinv, beff + 256, h3, n);

  pool_mlp<<<ng, 256, 0, stream>>>(h1, h2, h3, batch, n, lin1w, lin1b, lin2w, lin2b,
                                   (float*)d_out);
}